// Round 6
// baseline (177.015 us; speedup 1.0000x reference)
//
#include <hip/hip_runtime.h>
#include <hip/hip_bf16.h>

using bf16x8 = __attribute__((ext_vector_type(8))) __bf16;
using f32x4  = __attribute__((ext_vector_type(4))) float;
typedef unsigned int u32;

#define DFEAT 512
#define SLOTS 64
#define BM 32            // nodes per fused block
#define BK 64            // k-slice

static __device__ __forceinline__ unsigned short f2bfbits(float f) {
    union { float f; unsigned int u; } v; v.f = f;
    unsigned int u = v.u;
    unsigned int r = (u + 0x7fffu + ((u >> 16) & 1u)) >> 16;
    return (unsigned short)r;
}

// async global->LDS, 16B per lane: LDS dest = wave-uniform base + lane*16
static __device__ __forceinline__ void gload16(const unsigned short* g, unsigned short* l) {
    __builtin_amdgcn_global_load_lds(
        (const __attribute__((address_space(1))) u32*)g,
        (__attribute__((address_space(3))) u32*)l, 16, 0, 0);
}

// -------- prep: W fp32->bf16 + vs=W^T a_src, vd=W^T a_dst || edge slot-scatter ----
// Blocks [0,32): 16 W-rows each; thread t owns cols {t, t+256}; per-block partial
// column-dots reduced via fp32 atomics into vs/vd (zeroed by memset).
// Blocks [32,..): slot-scatter edges by dst, 4 items/thread.
__global__ __launch_bounds__(256) void prep_kernel(
    const float* __restrict__ Wm, const float* __restrict__ a_src,
    const float* __restrict__ a_dst,
    unsigned short* __restrict__ Wb, float* __restrict__ vs, float* __restrict__ vd,
    const int* __restrict__ srcv, const int* __restrict__ dstv,
    int* __restrict__ cur, int* __restrict__ slot, int E, int T)
{
    int b = blockIdx.x;
    int t = threadIdx.x;
    if (b < 32) {
        float s0 = 0.f, s1 = 0.f, d0 = 0.f, d1 = 0.f;
        #pragma unroll 4
        for (int r = 0; r < 16; ++r) {
            int j = b * 16 + r;
            float aj_s = a_src[j], aj_d = a_dst[j];
            float w0 = Wm[(size_t)j * DFEAT + t];
            float w1 = Wm[(size_t)j * DFEAT + t + 256];
            Wb[(size_t)j * DFEAT + t]       = f2bfbits(w0);
            Wb[(size_t)j * DFEAT + t + 256] = f2bfbits(w1);
            s0 += w0 * aj_s; s1 += w1 * aj_s;
            d0 += w0 * aj_d; d1 += w1 * aj_d;
        }
        atomicAdd(&vs[t], s0); atomicAdd(&vs[t + 256], s1);
        atomicAdd(&vd[t], d0); atomicAdd(&vd[t + 256], d1);
    } else {
        int base = (b - 32) * 1024 + t;
        #pragma unroll
        for (int it = 0; it < 4; ++it) {
            int i = base + it * 256;
            if (i < T) {
                int s, d;
                if (i < E) { s = srcv[i]; d = dstv[i]; }
                else       { s = d = i - E; }          // self-loops appended
                int pos = atomicAdd(&cur[d], 1);
                if (pos < SLOTS) slot[(size_t)d * SLOTS + pos] = s;
            }
        }
    }
}

// -------- cvt_x: x fp32->bf16 + es[n]=x[n].vs, ed[n]=x[n].vd (fp32, exact path) --
// One wave per row; lane owns 8 contiguous features.
__global__ __launch_bounds__(256) void cvt_x_kernel(
    const float* __restrict__ x, const float* __restrict__ vs,
    const float* __restrict__ vd,
    unsigned short* __restrict__ Xb, float* __restrict__ es, float* __restrict__ ed,
    int N)
{
    int node = (blockIdx.x * 256 + threadIdx.x) >> 6;
    int lane = threadIdx.x & 63;
    if (node >= N) return;
    const float* xr = x + (size_t)node * DFEAT + lane * 8;
    float4 v0 = *(const float4*)xr;
    float4 v1 = *(const float4*)(xr + 4);
    ushort4 u0, u1;
    u0.x = f2bfbits(v0.x); u0.y = f2bfbits(v0.y);
    u0.z = f2bfbits(v0.z); u0.w = f2bfbits(v0.w);
    u1.x = f2bfbits(v1.x); u1.y = f2bfbits(v1.y);
    u1.z = f2bfbits(v1.z); u1.w = f2bfbits(v1.w);
    *(ushort4*)(Xb + (size_t)node * DFEAT + lane * 8)     = u0;
    *(ushort4*)(Xb + (size_t)node * DFEAT + lane * 8 + 4) = u1;
    float4 s0 = *(const float4*)(vs + lane * 8);
    float4 s1 = *(const float4*)(vs + lane * 8 + 4);
    float4 d0 = *(const float4*)(vd + lane * 8);
    float4 d1 = *(const float4*)(vd + lane * 8 + 4);
    float ps = v0.x*s0.x + v0.y*s0.y + v0.z*s0.z + v0.w*s0.w
             + v1.x*s1.x + v1.y*s1.y + v1.z*s1.z + v1.w*s1.w;
    float pd = v0.x*d0.x + v0.y*d0.y + v0.z*d0.z + v0.w*d0.w
             + v1.x*d1.x + v1.y*d1.y + v1.z*d1.z + v1.w*d1.w;
    #pragma unroll
    for (int m = 1; m < 64; m <<= 1) {
        ps += __shfl_xor(ps, m);
        pd += __shfl_xor(pd, m);
    }
    if (lane == 0) { es[node] = ps; ed[node] = pd; }
}

// -------- fused gather-GEMM: out = x + elu((sum_e alpha*Xb[src]) W^T + bias) ------
// Exploits linearity: aggregation commutes with projection, so H never exists.
// Block = 32 nodes x all 512 cols, 512 threads (8 waves; wave w -> cols w*64..+63).
// Prologue: per-node softmax weights (alpha) into LDS (es/ed precomputed in fp32).
// 8 K-steps (BK=64), double-buffered:
//   stageB: W k-slice [512][64] via gload16, source chunk pre-XORed (row&7)     (T3)
//   gatherA: thread (node=tid>>4, sub=tid&15) accumulates sum_j w_j*Xb[src_j][k-sub]
//            (8B loads, 8 in flight), *inv_denom, cvt->bf16, swizzled ds_write
//   compute: ds_read A/B (same XOR) + 16 MFMA/wave; one __syncthreads drain/step.
// Gather traffic (174 MB, unchanged vs old aggregate) now overlaps MFMA + W-stream.
// LDS: B 2x64K + A 2x4K + lists 16K+ = ~152 KiB -> 1 block/CU.
// Epilogue: +bias, elu, +x residual -> out (no H, no es/ed atomics).
__global__ __launch_bounds__(512, 1) void gat_fused_kernel(
    const unsigned short* __restrict__ Xb, const unsigned short* __restrict__ Wb,
    const float* __restrict__ x, const float* __restrict__ bias,
    const int* __restrict__ cur, const int* __restrict__ slot,
    const float* __restrict__ es, const float* __restrict__ ed,
    float* __restrict__ out, int N)
{
    __shared__ __align__(16) unsigned short Bsm[2][512 * 64];   // 64 KiB each
    __shared__ __align__(16) unsigned short Asm[2][BM * 64];    //  4 KiB each
    __shared__ int   srcS[BM][SLOTS];
    __shared__ float wS[BM][SLOTS + 1];        // +1 pad: denom pass bank spread
    __shared__ float invS[BM];
    __shared__ int   kcntS[BM];

    int tid  = threadIdx.x;
    int wave = tid >> 6;
    int lane = tid & 63;
    int l15  = lane & 15;
    int quad = lane >> 4;
    int n0   = blockIdx.x * BM;

    // ---- per-node neighbor counts ----
    if (tid < BM) {
        int node = n0 + tid;
        int k = (node < N) ? cur[node] : 0;
        kcntS[tid] = k > SLOTS ? SLOTS : k;
    }
    __syncthreads();

    // ---- softmax weights into LDS ----
    for (int idx = tid; idx < BM * SLOTS; idx += 512) {
        int nn = idx >> 6, j = idx & 63;
        float w = 0.f; int s = 0;
        if (j < kcntS[nn]) {
            int node = n0 + nn;
            s = slot[(size_t)node * SLOTS + j];
            float e = es[s] + ed[node];
            e = e > 0.f ? e : 0.2f * e;        // leaky_relu
            w = __expf(e);                      // |e| small: no max-subtraction
        }
        srcS[nn][j] = s;
        wS[nn][j] = w;
    }

    // ---- B staging setup (issue step-0 loads early, they only write Bsm[0]) ----
    int brl    = lane >> 3;                    // row within wave's 8-row group
    int bchunk = (lane & 7) ^ brl;             // pre-swizzled source chunk
    auto stageB = [&](int buf, int s) {
        int ko = s * BK;
        #pragma unroll
        for (int p = 0; p < 8; ++p) {
            int n = wave * 8 + p * 64 + brl;
            gload16(Wb + (size_t)n * DFEAT + ko + bchunk * 8,
                    &Bsm[buf][(size_t)(wave * 8 + p * 64) * 64]);
        }
    };
    stageB(0, 0);
    __syncthreads();

    if (tid < BM) {
        float d = 0.f;
        int k = kcntS[tid];
        for (int j = 0; j < k; ++j) d += wS[tid][j];
        invS[tid] = (k > 0) ? 1.0f / d : 0.f;
    }
    __syncthreads();

    // ---- gather-accumulate A tile (G rows) ----
    int gn   = tid >> 4;                       // node 0..31
    int gsub = tid & 15;                       // 8B sub-chunk (4 bf16)
    int goff = gsub * 8;                       // byte offset within k-slice
    int adst = gn * 128 + (((gsub >> 1) ^ (gn & 7)) * 16) + (gsub & 1) * 8;
    const char* Xc = (const char*)Xb;

    auto gatherA = [&](int buf, int s) {
        int ko2 = s * BK * 2;                  // byte offset of k-slice in Xb row
        int kc = kcntS[gn];
        float a0 = 0.f, a1 = 0.f, a2 = 0.f, a3 = 0.f;
        auto fma4 = [&](uint2 h, float w) {
            a0 += w * __uint_as_float(h.x << 16);
            a1 += w * __uint_as_float(h.x & 0xffff0000u);
            a2 += w * __uint_as_float(h.y << 16);
            a3 += w * __uint_as_float(h.y & 0xffff0000u);
        };
        int j = 0;
        for (; j + 7 < kc; j += 8) {           // 8 gathers in flight
            int   q0 = srcS[gn][j],   q1 = srcS[gn][j+1];
            int   q2 = srcS[gn][j+2], q3 = srcS[gn][j+3];
            int   q4 = srcS[gn][j+4], q5 = srcS[gn][j+5];
            int   q6 = srcS[gn][j+6], q7 = srcS[gn][j+7];
            float w0 = wS[gn][j],   w1 = wS[gn][j+1];
            float w2 = wS[gn][j+2], w3 = wS[gn][j+3];
            float w4 = wS[gn][j+4], w5 = wS[gn][j+5];
            float w6 = wS[gn][j+6], w7 = wS[gn][j+7];
            uint2 h0 = *(const uint2*)(Xc + (size_t)q0 * 1024 + ko2 + goff);
            uint2 h1 = *(const uint2*)(Xc + (size_t)q1 * 1024 + ko2 + goff);
            uint2 h2 = *(const uint2*)(Xc + (size_t)q2 * 1024 + ko2 + goff);
            uint2 h3 = *(const uint2*)(Xc + (size_t)q3 * 1024 + ko2 + goff);
            uint2 h4 = *(const uint2*)(Xc + (size_t)q4 * 1024 + ko2 + goff);
            uint2 h5 = *(const uint2*)(Xc + (size_t)q5 * 1024 + ko2 + goff);
            uint2 h6 = *(const uint2*)(Xc + (size_t)q6 * 1024 + ko2 + goff);
            uint2 h7 = *(const uint2*)(Xc + (size_t)q7 * 1024 + ko2 + goff);
            fma4(h0, w0); fma4(h1, w1); fma4(h2, w2); fma4(h3, w3);
            fma4(h4, w4); fma4(h5, w5); fma4(h6, w6); fma4(h7, w7);
        }
        if (j + 3 < kc) {
            int   q0 = srcS[gn][j],   q1 = srcS[gn][j+1];
            int   q2 = srcS[gn][j+2], q3 = srcS[gn][j+3];
            float w0 = wS[gn][j],   w1 = wS[gn][j+1];
            float w2 = wS[gn][j+2], w3 = wS[gn][j+3];
            uint2 h0 = *(const uint2*)(Xc + (size_t)q0 * 1024 + ko2 + goff);
            uint2 h1 = *(const uint2*)(Xc + (size_t)q1 * 1024 + ko2 + goff);
            uint2 h2 = *(const uint2*)(Xc + (size_t)q2 * 1024 + ko2 + goff);
            uint2 h3 = *(const uint2*)(Xc + (size_t)q3 * 1024 + ko2 + goff);
            fma4(h0, w0); fma4(h1, w1); fma4(h2, w2); fma4(h3, w3);
            j += 4;
        }
        for (; j < kc; ++j) {
            uint2 hv = *(const uint2*)(Xc + (size_t)srcS[gn][j] * 1024 + ko2 + goff);
            fma4(hv, wS[gn][j]);
        }
        float inv = invS[gn];
        ushort4 o;
        o.x = f2bfbits(a0 * inv); o.y = f2bfbits(a1 * inv);
        o.z = f2bfbits(a2 * inv); o.w = f2bfbits(a3 * inv);
        *(ushort4*)((char*)&Asm[buf][0] + adst) = o;
    };

    f32x4 acc[2][4] = {};
    int xa = l15 & 7;
    auto compute = [&](int buf) {
        const char* Ab = (const char*)&Asm[buf][0];
        const char* Bb = (const char*)&Bsm[buf][0];
        #pragma unroll
        for (int ks = 0; ks < 2; ++ks) {
            int cb = ((ks * 4 + quad) ^ xa) * 16;
            bf16x8 a0 = *(const bf16x8*)(Ab + (0 * 16 + l15) * 128 + cb);
            bf16x8 a1 = *(const bf16x8*)(Ab + (1 * 16 + l15) * 128 + cb);
            bf16x8 b0 = *(const bf16x8*)(Bb + (size_t)(wave * 64 +  0 + l15) * 128 + cb);
            bf16x8 b1 = *(const bf16x8*)(Bb + (size_t)(wave * 64 + 16 + l15) * 128 + cb);
            bf16x8 b2 = *(const bf16x8*)(Bb + (size_t)(wave * 64 + 32 + l15) * 128 + cb);
            bf16x8 b3 = *(const bf16x8*)(Bb + (size_t)(wave * 64 + 48 + l15) * 128 + cb);
            acc[0][0] = __builtin_amdgcn_mfma_f32_16x16x32_bf16(a0, b0, acc[0][0], 0, 0, 0);
            acc[1][0] = __builtin_amdgcn_mfma_f32_16x16x32_bf16(a1, b0, acc[1][0], 0, 0, 0);
            acc[0][1] = __builtin_amdgcn_mfma_f32_16x16x32_bf16(a0, b1, acc[0][1], 0, 0, 0);
            acc[1][1] = __builtin_amdgcn_mfma_f32_16x16x32_bf16(a1, b1, acc[1][1], 0, 0, 0);
            acc[0][2] = __builtin_amdgcn_mfma_f32_16x16x32_bf16(a0, b2, acc[0][2], 0, 0, 0);
            acc[1][2] = __builtin_amdgcn_mfma_f32_16x16x32_bf16(a1, b2, acc[1][2], 0, 0, 0);
            acc[0][3] = __builtin_amdgcn_mfma_f32_16x16x32_bf16(a0, b3, acc[0][3], 0, 0, 0);
            acc[1][3] = __builtin_amdgcn_mfma_f32_16x16x32_bf16(a1, b3, acc[1][3], 0, 0, 0);
        }
    };

    gatherA(0, 0);
    __syncthreads();                           // drains stage-0 vmcnt + A writes
    int buf = 0;
    for (int s = 0; s < 7; ++s) {
        stageB(buf ^ 1, s + 1);                // async W loads fly under gather+MFMA
        gatherA(buf ^ 1, s + 1);
        compute(buf);
        __syncthreads();
        buf ^= 1;
    }
    compute(buf);

    // ---- epilogue: +bias, elu, +x residual ----
    float bcol[4];
    #pragma unroll
    for (int nt = 0; nt < 4; ++nt) bcol[nt] = bias[wave * 64 + nt * 16 + l15];
    #pragma unroll
    for (int mt = 0; mt < 2; ++mt) {
        #pragma unroll
        for (int r = 0; r < 4; ++r) {
            int node = n0 + mt * 16 + quad * 4 + r;
            if (node < N) {
                #pragma unroll
                for (int nt = 0; nt < 4; ++nt) {
                    int col = wave * 64 + nt * 16 + l15;
                    float v = acc[mt][nt][r] + bcol[nt];
                    v = v > 0.f ? v : __expf(v) - 1.f;   // elu
                    out[(size_t)node * DFEAT + col] = x[(size_t)node * DFEAT + col] + v;
                }
            }
        }
    }
}

extern "C" void kernel_launch(void* const* d_in, const int* in_sizes, int n_in,
                              void* d_out, int out_size, void* d_ws, size_t ws_size,
                              hipStream_t stream)
{
    const float* x    = (const float*)d_in[0];
    const int*   edge = (const int*)d_in[1];
    const float* Wm   = (const float*)d_in[2];
    const float* avs  = (const float*)d_in[3];
    const float* avd  = (const float*)d_in[4];
    const float* bias = (const float*)d_in[5];

    const int D = DFEAT;
    const int N = in_sizes[0] / D;
    const int E = in_sizes[1] / 2;
    const int T = E + N;
    const int* srcv = edge;
    const int* dstv = edge + E;

    char* ws = (char*)d_ws;
    size_t off = 0;
    auto alloc = [&](size_t bytes) -> char* {
        char* p = ws + off;
        off += (bytes + 255) & ~(size_t)255;
        return p;
    };
    // zero region: cur[N] | vs[512] | vd[512]
    size_t curBytes = (size_t)N * 4;
    size_t vsOff    = (curBytes + 255) & ~(size_t)255;
    char*  zbase    = alloc(vsOff + 4096);
    int*   cur = (int*)zbase;
    float* vs  = (float*)(zbase + vsOff);
    float* vd  = vs + 512;
    int*   slot = (int*)alloc((size_t)N * SLOTS * 4);
    unsigned short* Xb = (unsigned short*)alloc((size_t)N * D * 2);
    unsigned short* Wb = (unsigned short*)alloc((size_t)D * D * 2);
    float* es = (float*)alloc((size_t)N * 4);
    float* ed = (float*)alloc((size_t)N * 4);

    hipMemsetAsync(zbase, 0, vsOff + 4096, stream);

    int Gscat = (T + 1023) / 1024;
    prep_kernel<<<dim3(32 + Gscat), 256, 0, stream>>>(
        Wm, avs, avd, Wb, vs, vd, srcv, dstv, cur, slot, E, T);

    cvt_x_kernel<<<dim3((N * 64 + 255) / 256), 256, 0, stream>>>(
        x, vs, vd, Xb, es, ed, N);

    int nodeBlocks = (N + BM - 1) / BM;
    gat_fused_kernel<<<dim3(nodeBlocks), 512, 0, stream>>>(
        Xb, Wb, x, bias, cur, slot, es, ed, (float*)d_out, N);
}

// Round 7
// 147.984 us; speedup vs baseline: 1.1962x; 1.1962x over previous
//
#include <hip/hip_runtime.h>
#include <hip/hip_bf16.h>

using bf16x8 = __attribute__((ext_vector_type(8))) __bf16;
using f32x4  = __attribute__((ext_vector_type(4))) float;
typedef unsigned int u32;

#define DFEAT 512
#define SLOTS 64

static __device__ __forceinline__ unsigned short f2bfbits(float f) {
    union { float f; unsigned int u; } v; v.f = f;
    unsigned int u = v.u;
    unsigned int r = (u + 0x7fffu + ((u >> 16) & 1u)) >> 16;
    return (unsigned short)r;
}

// RNE fp32x8 -> bf16x8 (v_cvt_pk_bf16_f32; numerically == f2bfbits)
static __device__ __forceinline__ bf16x8 cvt8(float4 u, float4 v) {
    bf16x8 r;
    r[0] = (__bf16)u.x; r[1] = (__bf16)u.y; r[2] = (__bf16)u.z; r[3] = (__bf16)u.w;
    r[4] = (__bf16)v.x; r[5] = (__bf16)v.y; r[6] = (__bf16)v.z; r[7] = (__bf16)v.w;
    return r;
}

// async global->LDS, 16B per lane: LDS dest = wave-uniform base + lane*16
static __device__ __forceinline__ void gload16(const unsigned short* g, unsigned short* l) {
    __builtin_amdgcn_global_load_lds(
        (const __attribute__((address_space(1))) u32*)g,
        (__attribute__((address_space(3))) u32*)l, 16, 0, 0);
}

// -------- prep: W fp32->bf16 convert + slot-scatter edges by dst --------
// (X is no longer converted: the GEMM reads fp32 X directly, so the 31 MB
// cvt_x pass disappears.)
__global__ __launch_bounds__(256) void prep_kernel(
    const float* __restrict__ w, unsigned short* __restrict__ Wb,
    const int* __restrict__ srcv, const int* __restrict__ dstv,
    int* __restrict__ cur, int* __restrict__ slot,
    int nw4, int E, int T)
{
    int i = blockIdx.x * 256 + threadIdx.x;
    if (i < nw4) {
        float4 v = ((const float4*)w)[i];
        ushort4 u;
        u.x = f2bfbits(v.x); u.y = f2bfbits(v.y);
        u.z = f2bfbits(v.z); u.w = f2bfbits(v.w);
        ((ushort4*)Wb)[i] = u;
    }
    if (i < T) {
        int s, d;
        if (i < E) { s = srcv[i]; d = dstv[i]; }
        else       { s = d = i - E; }          // self-loops appended
        int pos = atomicAdd(&cur[d], 1);
        if (pos < SLOTS) slot[(size_t)d * SLOTS + pos] = s;
    }
}

// -------- GEMM: H[m][n] = sum_k X[m][k]*W[n][k], LDS double-buffer ----
// Tile 128x64, BK=64, 4 waves (wave w -> rows bm+w*32..+31, all 64 cols).
// B (W rows, bf16) staged via global_load_lds width=16, source chunk pre-XORed.
// A (X rows) read as FP32 from global with T14 async-split staging:
//   issue 8 float4 loads for step s+1  ->  compute(s) MFMA (independent)
//   ->  cvt->bf16 + swizzled ds_write  ->  barrier.
// FP32 load latency hides under the MFMA phase (R1's failure was waiting at
// the convert, before compute). X re-reads across the 8 col-panels of a row
// panel stay on one XCD (swizzle) -> L2 hits; HBM reads X once (20 MB) vs the
// old cvt-pass route's 31 MB + 10 MB Xb.
// Swizzle involution (rule #21): write chunk c^(row&7), read chunk (ks*4+quad)^(l15&7).
// LDS 48KiB -> 3 blocks/CU; grid 640 blocks.
// Frags: A: lane holds A[m=lane&15][k=quad*8+j]; B[k][n=lane&15]=W[n][k];
// C/D col=lane&15, row=quad*4+r.
__global__ __launch_bounds__(256, 3) void gemm_h_kernel(
    const float* __restrict__ Xf, const unsigned short* __restrict__ Wm,
    const float* __restrict__ avs, const float* __restrict__ avd,
    unsigned short* __restrict__ H, float* __restrict__ es, float* __restrict__ ed,
    int N)
{
    __shared__ __align__(16) unsigned short Asm[2][128 * 64];  // 16 KiB/buf
    __shared__ __align__(16) unsigned short Bsm[2][64 * 64];   //  8 KiB/buf

    int L = blockIdx.x;
    int xcd = L & 7;
    int q   = L >> 3;
    int rpan = (q >> 3) * 8 + xcd;             // row panel (128 rows)
    int cpan = q & 7;                          // col panel (64 cols)
    int rowPanels = (N + 127) >> 7;
    if (rpan >= rowPanels) return;
    int bm = rpan * 128;
    int bn = cpan * 64;

    int tid  = threadIdx.x;
    int wave = tid >> 6;
    int lane = tid & 63;
    int l15  = lane & 15;
    int quad = lane >> 4;

    // ---- B staging: lane l covers row (l>>3), chunk (l&7) of an 8x64 sub-tile ----
    int srow   = lane >> 3;                    // 0..7
    int schunk = (lane & 7) ^ srow;            // inverse-swizzled source chunk
    const unsigned short* gB0 = Wm + (size_t)(bn + wave * 16 + srow) * DFEAT + schunk * 8;
    const unsigned short* gB1 = gB0 + (size_t)8 * DFEAT;

    auto stageB = [&](int buf, int s) {
        int ko = s * 64;
        gload16(gB0 + ko, &Bsm[buf][(wave * 16 + 0) * 64]);
        gload16(gB1 + ko, &Bsm[buf][(wave * 16 + 8) * 64]);
    };

    // ---- A staging (fp32 -> regs -> bf16 -> swizzled LDS) ----
    // lane covers row (lane>>1) of the wave's 32 rows, chunks (lane&1)*4..+3
    int arl   = lane >> 1;                     // 0..31 local row
    int ac0   = (lane & 1) * 4;                // first 16B-bf16 chunk (8 k each)
    int arow  = bm + wave * 32 + arl;
    arow = arow < N ? arow : N - 1;            // clamp: garbage rows never stored
    const float* gA = Xf + (size_t)arow * DFEAT + ac0 * 8;
    int ldsrow = wave * 32 + arl;
    char* AbW0 = (char*)&Asm[0][0] + ldsrow * 128;
    char* AbW1 = (char*)&Asm[1][0] + ldsrow * 128;
    int axor = arl & 7;

    float4 av[8];
    auto aload = [&](int s) {
        const float* p = gA + s * 64;
        #pragma unroll
        for (int i = 0; i < 4; ++i) {
            av[2 * i]     = *(const float4*)(p + i * 8);
            av[2 * i + 1] = *(const float4*)(p + i * 8 + 4);
        }
    };
    auto awrite = [&](int buf) {
        char* Ab = buf ? AbW1 : AbW0;
        #pragma unroll
        for (int i = 0; i < 4; ++i) {
            bf16x8 o = cvt8(av[2 * i], av[2 * i + 1]);
            *(bf16x8*)(Ab + (((ac0 + i) ^ axor) * 16)) = o;
        }
    };

    f32x4 acc[2][4] = {};
    int xa = l15 & 7;                          // row&7 for this lane's A/B rows
    int aoff0 = (wave * 32 +  0 + l15) * 128;  // A row byte offsets (read side)
    int aoff1 = (wave * 32 + 16 + l15) * 128;

    auto compute = [&](int buf) {
        const char* Ab = (const char*)&Asm[buf][0];
        const char* Bb = (const char*)&Bsm[buf][0];
        #pragma unroll
        for (int ks = 0; ks < 2; ++ks) {
            int cb = ((ks * 4 + quad) ^ xa) * 16;   // swizzled chunk byte
            bf16x8 a0 = *(const bf16x8*)(Ab + aoff0 + cb);
            bf16x8 a1 = *(const bf16x8*)(Ab + aoff1 + cb);
            bf16x8 b0 = *(const bf16x8*)(Bb + (0 * 16 + l15) * 128 + cb);
            bf16x8 b1 = *(const bf16x8*)(Bb + (1 * 16 + l15) * 128 + cb);
            bf16x8 b2 = *(const bf16x8*)(Bb + (2 * 16 + l15) * 128 + cb);
            bf16x8 b3 = *(const bf16x8*)(Bb + (3 * 16 + l15) * 128 + cb);
            acc[0][0] = __builtin_amdgcn_mfma_f32_16x16x32_bf16(a0, b0, acc[0][0], 0, 0, 0);
            acc[1][0] = __builtin_amdgcn_mfma_f32_16x16x32_bf16(a1, b0, acc[1][0], 0, 0, 0);
            acc[0][1] = __builtin_amdgcn_mfma_f32_16x16x32_bf16(a0, b1, acc[0][1], 0, 0, 0);
            acc[1][1] = __builtin_amdgcn_mfma_f32_16x16x32_bf16(a1, b1, acc[1][1], 0, 0, 0);
            acc[0][2] = __builtin_amdgcn_mfma_f32_16x16x32_bf16(a0, b2, acc[0][2], 0, 0, 0);
            acc[1][2] = __builtin_amdgcn_mfma_f32_16x16x32_bf16(a1, b2, acc[1][2], 0, 0, 0);
            acc[0][3] = __builtin_amdgcn_mfma_f32_16x16x32_bf16(a0, b3, acc[0][3], 0, 0, 0);
            acc[1][3] = __builtin_amdgcn_mfma_f32_16x16x32_bf16(a1, b3, acc[1][3], 0, 0, 0);
        }
    };

    // prologue: stage step 0 (B async + A reg->LDS), drain, then pipeline
    stageB(0, 0);
    aload(0);
    awrite(0);
    __syncthreads();
    int buf = 0;
    for (int s = 0; s < 7; ++s) {
        stageB(buf ^ 1, s + 1);                // async B loads for s+1
        aload(s + 1);                          // issue A fp32 loads for s+1
        compute(buf);                          // MFMA on s (independent of aloads)
        awrite(buf ^ 1);                       // vmcnt-wait + cvt + ds_write
        __syncthreads();
        buf ^= 1;
    }
    compute(buf);                              // last step

    // ---- epilogue: H store + fused e_src/e_dst partial dot + atomic reduce ----
    float as[4], ad[4];
    #pragma unroll
    for (int nt = 0; nt < 4; ++nt) {
        as[nt] = avs[bn + nt * 16 + l15];
        ad[nt] = avd[bn + nt * 16 + l15];
    }

    #pragma unroll
    for (int mt = 0; mt < 2; ++mt) {
        int rbase = bm + wave * 32 + mt * 16 + quad * 4;
        #pragma unroll
        for (int nt = 0; nt < 4; ++nt) {
            int col = bn + nt * 16 + l15;
            #pragma unroll
            for (int r = 0; r < 4; ++r) {
                int row = rbase + r;
                if (row < N) H[(size_t)row * DFEAT + col] = f2bfbits(acc[mt][nt][r]);
            }
        }
        #pragma unroll
        for (int r = 0; r < 4; ++r) {
            float ps = acc[mt][0][r] * as[0] + acc[mt][1][r] * as[1]
                     + acc[mt][2][r] * as[2] + acc[mt][3][r] * as[3];
            float pd = acc[mt][0][r] * ad[0] + acc[mt][1][r] * ad[1]
                     + acc[mt][2][r] * ad[2] + acc[mt][3][r] * ad[3];
            #pragma unroll
            for (int m = 1; m < 16; m <<= 1) {
                ps += __shfl_xor(ps, m);
                pd += __shfl_xor(pd, m);
            }
            int row = rbase + r;
            if (l15 == 0 && row < N) {
                atomicAdd(&es[row], ps);
                atomicAdd(&ed[row], pd);
            }
        }
    }
}

// -------- aggregate: one WAVE per node; lane j owns slot j; 16B/lane row reads;
//          8 row-gathers in flight --------
__global__ __launch_bounds__(256) void aggregate_kernel(
    const unsigned short* __restrict__ H, const float* __restrict__ x,
    const float* __restrict__ bias,
    const int* __restrict__ cur, const int* __restrict__ slot,
    const float* __restrict__ es, const float* __restrict__ ed,
    float* __restrict__ out, int N)
{
    int node = (blockIdx.x * 256 + threadIdx.x) >> 6;
    int lane = threadIdx.x & 63;
    if (node >= N) return;

    int k = cur[node];
    if (k > SLOTS) k = SLOTS;

    int   s = 0;
    float w = 0.f;
    if (lane < k) {
        s = slot[(size_t)node * SLOTS + lane];
        float e = es[s] + ed[node];
        e = e > 0.f ? e : 0.2f * e;            // leaky_relu
        w = __expf(e);                          // |e| small: no max-subtraction needed
    }
    float denom = w;
    #pragma unroll
    for (int off = 32; off > 0; off >>= 1) denom += __shfl_xor(denom, off);
    float inv = 1.0f / denom;

    float a[8] = {};
    const unsigned short* Hl = H + lane * 8;   // this lane's 8 features (16 B)

    auto fma8 = [&](uint4 hv, float wj) {
        a[0] += wj * __uint_as_float(hv.x << 16);
        a[1] += wj * __uint_as_float(hv.x & 0xffff0000u);
        a[2] += wj * __uint_as_float(hv.y << 16);
        a[3] += wj * __uint_as_float(hv.y & 0xffff0000u);
        a[4] += wj * __uint_as_float(hv.z << 16);
        a[5] += wj * __uint_as_float(hv.z & 0xffff0000u);
        a[6] += wj * __uint_as_float(hv.w << 16);
        a[7] += wj * __uint_as_float(hv.w & 0xffff0000u);
    };

    int j = 0;
    for (; j + 7 < k; j += 8) {                // 8 row-gathers in flight
        int   s0 = __shfl(s, j),     s1 = __shfl(s, j + 1);
        int   s2 = __shfl(s, j + 2), s3 = __shfl(s, j + 3);
        int   s4 = __shfl(s, j + 4), s5 = __shfl(s, j + 5);
        int   s6 = __shfl(s, j + 6), s7 = __shfl(s, j + 7);
        float w0 = __shfl(w, j),     w1 = __shfl(w, j + 1);
        float w2 = __shfl(w, j + 2), w3 = __shfl(w, j + 3);
        float w4 = __shfl(w, j + 4), w5 = __shfl(w, j + 5);
        float w6 = __shfl(w, j + 6), w7 = __shfl(w, j + 7);
        uint4 h0 = *(const uint4*)(Hl + (size_t)s0 * DFEAT);
        uint4 h1 = *(const uint4*)(Hl + (size_t)s1 * DFEAT);
        uint4 h2 = *(const uint4*)(Hl + (size_t)s2 * DFEAT);
        uint4 h3 = *(const uint4*)(Hl + (size_t)s3 * DFEAT);
        uint4 h4 = *(const uint4*)(Hl + (size_t)s4 * DFEAT);
        uint4 h5 = *(const uint4*)(Hl + (size_t)s5 * DFEAT);
        uint4 h6 = *(const uint4*)(Hl + (size_t)s6 * DFEAT);
        uint4 h7 = *(const uint4*)(Hl + (size_t)s7 * DFEAT);
        fma8(h0, w0); fma8(h1, w1); fma8(h2, w2); fma8(h3, w3);
        fma8(h4, w4); fma8(h5, w5); fma8(h6, w6); fma8(h7, w7);
    }
    if (j + 3 < k) {                           // 4-wide step
        int   s0 = __shfl(s, j),     s1 = __shfl(s, j + 1);
        int   s2 = __shfl(s, j + 2), s3 = __shfl(s, j + 3);
        float w0 = __shfl(w, j),     w1 = __shfl(w, j + 1);
        float w2 = __shfl(w, j + 2), w3 = __shfl(w, j + 3);
        uint4 h0 = *(const uint4*)(Hl + (size_t)s0 * DFEAT);
        uint4 h1 = *(const uint4*)(Hl + (size_t)s1 * DFEAT);
        uint4 h2 = *(const uint4*)(Hl + (size_t)s2 * DFEAT);
        uint4 h3 = *(const uint4*)(Hl + (size_t)s3 * DFEAT);
        fma8(h0, w0); fma8(h1, w1); fma8(h2, w2); fma8(h3, w3);
        j += 4;
    }
    for (; j < k; ++j) {
        uint4 hv = *(const uint4*)(Hl + (size_t)__shfl(s, j) * DFEAT);
        fma8(hv, __shfl(w, j));
    }

    int c = lane * 8;
    float4 b0 = *(const float4*)(bias + c);
    float4 b1 = *(const float4*)(bias + c + 4);
    float4 x0 = *(const float4*)(x + (size_t)node * DFEAT + c);
    float4 x1 = *(const float4*)(x + (size_t)node * DFEAT + c + 4);
    float r[8];
    r[0] = a[0] * inv + b0.x; r[1] = a[1] * inv + b0.y;
    r[2] = a[2] * inv + b0.z; r[3] = a[3] * inv + b0.w;
    r[4] = a[4] * inv + b1.x; r[5] = a[5] * inv + b1.y;
    r[6] = a[6] * inv + b1.z; r[7] = a[7] * inv + b1.w;
    #pragma unroll
    for (int i = 0; i < 8; ++i)
        r[i] = r[i] > 0.f ? r[i] : __expf(r[i]) - 1.f;   // elu
    float4 o0 = make_float4(x0.x + r[0], x0.y + r[1], x0.z + r[2], x0.w + r[3]);
    float4 o1 = make_float4(x1.x + r[4], x1.y + r[5], x1.z + r[6], x1.w + r[7]);
    *(float4*)(out + (size_t)node * DFEAT + c)     = o0;
    *(float4*)(out + (size_t)node * DFEAT + c + 4) = o1;
}

extern "C" void kernel_launch(void* const* d_in, const int* in_sizes, int n_in,
                              void* d_out, int out_size, void* d_ws, size_t ws_size,
                              hipStream_t stream)
{
    const float* x    = (const float*)d_in[0];
    const int*   edge = (const int*)d_in[1];
    const float* Wm   = (const float*)d_in[2];
    const float* avs  = (const float*)d_in[3];
    const float* avd  = (const float*)d_in[4];
    const float* bias = (const float*)d_in[5];

    const int D = DFEAT;
    const int N = in_sizes[0] / D;
    const int E = in_sizes[1] / 2;
    const int T = E + N;
    const int* srcv = edge;
    const int* dstv = edge + E;

    char* ws = (char*)d_ws;
    size_t off = 0;
    auto alloc = [&](size_t bytes) -> char* {
        char* p = ws + off;
        off += (bytes + 255) & ~(size_t)255;
        return p;
    };
    // zero region: cur[N] | es[N] | ed[N]
    int*   cur  = (int*)alloc((size_t)N * 3 * 4);
    float* es   = (float*)(cur + N);
    float* ed   = es + N;
    int*   slot = (int*)alloc((size_t)N * SLOTS * 4);
    unsigned short* Wb = (unsigned short*)alloc((size_t)D * D * 2);
    unsigned short* H  = (unsigned short*)alloc((size_t)N * D * 2);

    hipMemsetAsync(cur, 0, (size_t)N * 3 * 4, stream);

    int nw4   = (D * D) / 4;
    int grid0 = (nw4 > T ? nw4 : T);
    prep_kernel<<<dim3((grid0 + 255) / 256), 256, 0, stream>>>(
        Wm, Wb, srcv, dstv, cur, slot, nw4, E, T);

    int rowPanels  = (N + 127) / 128;          // 128-row tiles
    int rowPanels8 = ((rowPanels + 7) / 8) * 8;
    gemm_h_kernel<<<dim3(rowPanels8 * 8), 256, 0, stream>>>(
        x, Wb, avs, avd, H, es, ed, N);
    aggregate_kernel<<<dim3((N * 64 + 255) / 256), 256, 0, stream>>>(
        H, x, bias, cur, slot, es, ed, (float*)d_out, N);
}

// Round 8
// 133.211 us; speedup vs baseline: 1.3288x; 1.1109x over previous
//
#include <hip/hip_runtime.h>
#include <hip/hip_bf16.h>

using bf16x8 = __attribute__((ext_vector_type(8))) __bf16;
using f32x4  = __attribute__((ext_vector_type(4))) float;
typedef unsigned int u32;

#define DFEAT 512
#define SLOTS 64

static __device__ __forceinline__ unsigned short f2bfbits(float f) {
    union { float f; unsigned int u; } v; v.f = f;
    unsigned int u = v.u;
    unsigned int r = (u + 0x7fffu + ((u >> 16) & 1u)) >> 16;
    return (unsigned short)r;
}

// async global->LDS, 16B per lane: LDS dest = wave-uniform base + lane*16
static __device__ __forceinline__ void gload16(const unsigned short* g, unsigned short* l) {
    __builtin_amdgcn_global_load_lds(
        (const __attribute__((address_space(1))) u32*)g,
        (__attribute__((address_space(3))) u32*)l, 16, 0, 0);
}

// -------- fused: fp32->bf16 convert (X,W) + slot-scatter edges by dst --------
__global__ __launch_bounds__(256) void cvt_scatter_kernel(
    const float* __restrict__ x, const float* __restrict__ w,
    unsigned short* __restrict__ Xb, unsigned short* __restrict__ Wb,
    const int* __restrict__ srcv, const int* __restrict__ dstv,
    int* __restrict__ cur, int* __restrict__ slot,
    int nx4, int ntot4, int E, int T)
{
    int i = blockIdx.x * 256 + threadIdx.x;
    if (i < ntot4) {
        const float* in = (i < nx4) ? x : w;
        unsigned short* o = (i < nx4) ? Xb : Wb;
        int j = (i < nx4) ? i : i - nx4;
        float4 v = ((const float4*)in)[j];
        ushort4 u;
        u.x = f2bfbits(v.x); u.y = f2bfbits(v.y);
        u.z = f2bfbits(v.z); u.w = f2bfbits(v.w);
        ((ushort4*)o)[j] = u;
    }
    if (i < T) {
        int s, d;
        if (i < E) { s = srcv[i]; d = dstv[i]; }
        else       { s = d = i - E; }          // self-loops appended
        int pos = atomicAdd(&cur[d], 1);
        if (pos < SLOTS) slot[(size_t)d * SLOTS + pos] = s;
    }
}

// -------- GEMM: H[m][n] = sum_k X[m][k]*W[n][k], counted-vmcnt pipeline (T4) ----
// Tile 128x64, BK=64, 4 waves (wave w -> rows bm+w*32..+31, all 64 cols).
// A and B staged via global_load_lds width=16 (8-row x 128B-contiguous lane map —
// per-lane A loads are 64-segment poison, confirmed R1/R7). Double-buffered with
// counted vmcnt: prologue stages steps 0,1; per step:
//   vmcnt(6) [s's 6 loads/wave landed, s+1's stay IN FLIGHT] -> barrier ->
//   compute(s) -> lgkmcnt(0) -> barrier [buf reads done] -> stage(s+2 into buf).
// Loads never drain to 0 in the loop (m233: the vmcnt(0)-before-barrier drain is
// ~72% of the 2-phase critical path; m218: counted-vs-drain0 = +38-73%).
// Swizzle (rule #21, both-sides involution): LDS dest linear; SOURCE chunk
// pre-XORed ((l&7)^srow); ds_read applies same XOR -> <=2-way bank aliasing.
// LDS 48KiB -> 3 blocks/CU; grid 640. XCD swizzle: 8 col-panels of a row panel
// share an XCD -> X re-reads L2-hit. Frags: A: lane holds A[m=lane&15][k=quad*8+j];
// B[k][n=lane&15]=W[n][k]; C/D col=lane&15, row=quad*4+r.
__global__ __launch_bounds__(256, 3) void gemm_h_kernel(
    const unsigned short* __restrict__ X, const unsigned short* __restrict__ Wm,
    const float* __restrict__ avs, const float* __restrict__ avd,
    unsigned short* __restrict__ H, float* __restrict__ es, float* __restrict__ ed,
    int N)
{
    __shared__ __align__(16) unsigned short Asm[2][128 * 64];  // 16 KiB/buf
    __shared__ __align__(16) unsigned short Bsm[2][64 * 64];   //  8 KiB/buf

    int L = blockIdx.x;
    int xcd = L & 7;
    int q   = L >> 3;
    int rpan = (q >> 3) * 8 + xcd;             // row panel (128 rows)
    int cpan = q & 7;                          // col panel (64 cols)
    int rowPanels = (N + 127) >> 7;
    if (rpan >= rowPanels) return;             // whole block exits: no barrier yet
    int bm = rpan * 128;
    int bn = cpan * 64;

    int tid  = threadIdx.x;
    int wave = tid >> 6;
    int lane = tid & 63;
    int l15  = lane & 15;
    int quad = lane >> 4;

    // ---- staging: lane l covers row (l>>3), 16B chunk (l&7) of an 8x64 sub-tile;
    //      source chunk pre-swizzled by row so linear LDS ends up swizzled ----
    int srow   = lane >> 3;                    // 0..7
    int schunk = (lane & 7) ^ srow;            // inverse-swizzled source chunk
    const unsigned short* gA0;
    const unsigned short* gA1;
    const unsigned short* gA2;
    const unsigned short* gA3;
    {
        int r0 = bm + wave * 32 +  0 + srow; r0 = r0 < N ? r0 : N - 1;
        int r1 = bm + wave * 32 +  8 + srow; r1 = r1 < N ? r1 : N - 1;
        int r2 = bm + wave * 32 + 16 + srow; r2 = r2 < N ? r2 : N - 1;
        int r3 = bm + wave * 32 + 24 + srow; r3 = r3 < N ? r3 : N - 1;
        gA0 = X + (size_t)r0 * DFEAT + schunk * 8;
        gA1 = X + (size_t)r1 * DFEAT + schunk * 8;
        gA2 = X + (size_t)r2 * DFEAT + schunk * 8;
        gA3 = X + (size_t)r3 * DFEAT + schunk * 8;
    }
    const unsigned short* gB0 = Wm + (size_t)(bn + wave * 16 + srow) * DFEAT + schunk * 8;
    const unsigned short* gB1 = gB0 + (size_t)8 * DFEAT;

    auto stage = [&](int buf, int s) {         // 6 loads/wave
        int ko = s * 64;                       // k-offset in elements
        gload16(gA0 + ko, &Asm[buf][(wave * 32 +  0) * 64]);
        gload16(gA1 + ko, &Asm[buf][(wave * 32 +  8) * 64]);
        gload16(gA2 + ko, &Asm[buf][(wave * 32 + 16) * 64]);
        gload16(gA3 + ko, &Asm[buf][(wave * 32 + 24) * 64]);
        gload16(gB0 + ko, &Bsm[buf][(wave * 16 + 0) * 64]);
        gload16(gB1 + ko, &Bsm[buf][(wave * 16 + 8) * 64]);
    };

    f32x4 acc[2][4] = {};
    int xa = l15 & 7;                          // row&7 for this lane's A/B rows
    int aoff0 = (wave * 32 +  0 + l15) * 128;  // A row byte offsets
    int aoff1 = (wave * 32 + 16 + l15) * 128;

    auto compute = [&](int buf) {
        const char* Ab = (const char*)&Asm[buf][0];
        const char* Bb = (const char*)&Bsm[buf][0];
        #pragma unroll
        for (int ks = 0; ks < 2; ++ks) {
            int cb = ((ks * 4 + quad) ^ xa) * 16;   // swizzled chunk byte
            bf16x8 a0 = *(const bf16x8*)(Ab + aoff0 + cb);
            bf16x8 a1 = *(const bf16x8*)(Ab + aoff1 + cb);
            bf16x8 b0 = *(const bf16x8*)(Bb + (0 * 16 + l15) * 128 + cb);
            bf16x8 b1 = *(const bf16x8*)(Bb + (1 * 16 + l15) * 128 + cb);
            bf16x8 b2 = *(const bf16x8*)(Bb + (2 * 16 + l15) * 128 + cb);
            bf16x8 b3 = *(const bf16x8*)(Bb + (3 * 16 + l15) * 128 + cb);
            acc[0][0] = __builtin_amdgcn_mfma_f32_16x16x32_bf16(a0, b0, acc[0][0], 0, 0, 0);
            acc[1][0] = __builtin_amdgcn_mfma_f32_16x16x32_bf16(a1, b0, acc[1][0], 0, 0, 0);
            acc[0][1] = __builtin_amdgcn_mfma_f32_16x16x32_bf16(a0, b1, acc[0][1], 0, 0, 0);
            acc[1][1] = __builtin_amdgcn_mfma_f32_16x16x32_bf16(a1, b1, acc[1][1], 0, 0, 0);
            acc[0][2] = __builtin_amdgcn_mfma_f32_16x16x32_bf16(a0, b2, acc[0][2], 0, 0, 0);
            acc[1][2] = __builtin_amdgcn_mfma_f32_16x16x32_bf16(a1, b2, acc[1][2], 0, 0, 0);
            acc[0][3] = __builtin_amdgcn_mfma_f32_16x16x32_bf16(a0, b3, acc[0][3], 0, 0, 0);
            acc[1][3] = __builtin_amdgcn_mfma_f32_16x16x32_bf16(a1, b3, acc[1][3], 0, 0, 0);
        }
    };

    // ---- counted-vmcnt pipeline: steps 0,1 staged; never drain to 0 in loop ----
    stage(0, 0);                               // out: 6
    stage(1, 1);                               // out: 12
    int buf = 0;
    #pragma unroll 1
    for (int s = 0; s < 7; ++s) {
        asm volatile("s_waitcnt vmcnt(6)" ::: "memory");   // s's landed; s+1 in flight
        __builtin_amdgcn_s_barrier();
        __builtin_amdgcn_sched_barrier(0);
        compute(buf);
        asm volatile("s_waitcnt lgkmcnt(0)" ::: "memory"); // buf reads complete
        __builtin_amdgcn_s_barrier();
        __builtin_amdgcn_sched_barrier(0);
        if (s < 6) stage(buf, s + 2);          // refill freed buffer (out: +6)
        buf ^= 1;
    }
    asm volatile("s_waitcnt vmcnt(0)" ::: "memory");       // step-7 loads landed
    __builtin_amdgcn_s_barrier();
    compute(buf);                              // last step

    // ---- epilogue: H store + fused e_src/e_dst partial dot + atomic reduce ----
    float as[4], ad[4];
    #pragma unroll
    for (int nt = 0; nt < 4; ++nt) {
        as[nt] = avs[bn + nt * 16 + l15];
        ad[nt] = avd[bn + nt * 16 + l15];
    }

    #pragma unroll
    for (int mt = 0; mt < 2; ++mt) {
        int rbase = bm + wave * 32 + mt * 16 + quad * 4;
        #pragma unroll
        for (int nt = 0; nt < 4; ++nt) {
            int col = bn + nt * 16 + l15;
            #pragma unroll
            for (int r = 0; r < 4; ++r) {
                int row = rbase + r;
                if (row < N) H[(size_t)row * DFEAT + col] = f2bfbits(acc[mt][nt][r]);
            }
        }
        #pragma unroll
        for (int r = 0; r < 4; ++r) {
            float ps = acc[mt][0][r] * as[0] + acc[mt][1][r] * as[1]
                     + acc[mt][2][r] * as[2] + acc[mt][3][r] * as[3];
            float pd = acc[mt][0][r] * ad[0] + acc[mt][1][r] * ad[1]
                     + acc[mt][2][r] * ad[2] + acc[mt][3][r] * ad[3];
            #pragma unroll
            for (int m = 1; m < 16; m <<= 1) {
                ps += __shfl_xor(ps, m);
                pd += __shfl_xor(pd, m);
            }
            int row = rbase + r;
            if (l15 == 0 && row < N) {
                atomicAdd(&es[row], ps);
                atomicAdd(&ed[row], pd);
            }
        }
    }
}

// -------- aggregate: one WAVE per node; lane j owns slot j; 16B/lane row reads;
//          8 row-gathers in flight --------
__global__ __launch_bounds__(256) void aggregate_kernel(
    const unsigned short* __restrict__ H, const float* __restrict__ x,
    const float* __restrict__ bias,
    const int* __restrict__ cur, const int* __restrict__ slot,
    const float* __restrict__ es, const float* __restrict__ ed,
    float* __restrict__ out, int N)
{
    int node = (blockIdx.x * 256 + threadIdx.x) >> 6;
    int lane = threadIdx.x & 63;
    if (node >= N) return;

    int k = cur[node];
    if (k > SLOTS) k = SLOTS;

    int   s = 0;
    float w = 0.f;
    if (lane < k) {
        s = slot[(size_t)node * SLOTS + lane];
        float e = es[s] + ed[node];
        e = e > 0.f ? e : 0.2f * e;            // leaky_relu
        w = __expf(e);                          // |e| small: no max-subtraction needed
    }
    float denom = w;
    #pragma unroll
    for (int off = 32; off > 0; off >>= 1) denom += __shfl_xor(denom, off);
    float inv = 1.0f / denom;

    float a[8] = {};
    const unsigned short* Hl = H + lane * 8;   // this lane's 8 features (16 B)

    auto fma8 = [&](uint4 hv, float wj) {
        a[0] += wj * __uint_as_float(hv.x << 16);
        a[1] += wj * __uint_as_float(hv.x & 0xffff0000u);
        a[2] += wj * __uint_as_float(hv.y << 16);
        a[3] += wj * __uint_as_float(hv.y & 0xffff0000u);
        a[4] += wj * __uint_as_float(hv.z << 16);
        a[5] += wj * __uint_as_float(hv.z & 0xffff0000u);
        a[6] += wj * __uint_as_float(hv.w << 16);
        a[7] += wj * __uint_as_float(hv.w & 0xffff0000u);
    };

    int j = 0;
    for (; j + 7 < k; j += 8) {                // 8 row-gathers in flight
        int   s0 = __shfl(s, j),     s1 = __shfl(s, j + 1);
        int   s2 = __shfl(s, j + 2), s3 = __shfl(s, j + 3);
        int   s4 = __shfl(s, j + 4), s5 = __shfl(s, j + 5);
        int   s6 = __shfl(s, j + 6), s7 = __shfl(s, j + 7);
        float w0 = __shfl(w, j),     w1 = __shfl(w, j + 1);
        float w2 = __shfl(w, j + 2), w3 = __shfl(w, j + 3);
        float w4 = __shfl(w, j + 4), w5 = __shfl(w, j + 5);
        float w6 = __shfl(w, j + 6), w7 = __shfl(w, j + 7);
        uint4 h0 = *(const uint4*)(Hl + (size_t)s0 * DFEAT);
        uint4 h1 = *(const uint4*)(Hl + (size_t)s1 * DFEAT);
        uint4 h2 = *(const uint4*)(Hl + (size_t)s2 * DFEAT);
        uint4 h3 = *(const uint4*)(Hl + (size_t)s3 * DFEAT);
        uint4 h4 = *(const uint4*)(Hl + (size_t)s4 * DFEAT);
        uint4 h5 = *(const uint4*)(Hl + (size_t)s5 * DFEAT);
        uint4 h6 = *(const uint4*)(Hl + (size_t)s6 * DFEAT);
        uint4 h7 = *(const uint4*)(Hl + (size_t)s7 * DFEAT);
        fma8(h0, w0); fma8(h1, w1); fma8(h2, w2); fma8(h3, w3);
        fma8(h4, w4); fma8(h5, w5); fma8(h6, w6); fma8(h7, w7);
    }
    if (j + 3 < k) {                           // 4-wide step
        int   s0 = __shfl(s, j),     s1 = __shfl(s, j + 1);
        int   s2 = __shfl(s, j + 2), s3 = __shfl(s, j + 3);
        float w0 = __shfl(w, j),     w1 = __shfl(w, j + 1);
        float w2 = __shfl(w, j + 2), w3 = __shfl(w, j + 3);
        uint4 h0 = *(const uint4*)(Hl + (size_t)s0 * DFEAT);
        uint4 h1 = *(const uint4*)(Hl + (size_t)s1 * DFEAT);
        uint4 h2 = *(const uint4*)(Hl + (size_t)s2 * DFEAT);
        uint4 h3 = *(const uint4*)(Hl + (size_t)s3 * DFEAT);
        fma8(h0, w0); fma8(h1, w1); fma8(h2, w2); fma8(h3, w3);
        j += 4;
    }
    for (; j < k; ++j) {
        uint4 hv = *(const uint4*)(Hl + (size_t)__shfl(s, j) * DFEAT);
        fma8(hv, __shfl(w, j));
    }

    int c = lane * 8;
    float4 b0 = *(const float4*)(bias + c);
    float4 b1 = *(const float4*)(bias + c + 4);
    float4 x0 = *(const float4*)(x + (size_t)node * DFEAT + c);
    float4 x1 = *(const float4*)(x + (size_t)node * DFEAT + c + 4);
    float r[8];
    r[0] = a[0] * inv + b0.x; r[1] = a[1] * inv + b0.y;
    r[2] = a[2] * inv + b0.z; r[3] = a[3] * inv + b0.w;
    r[4] = a[4] * inv + b1.x; r[5] = a[5] * inv + b1.y;
    r[6] = a[6] * inv + b1.z; r[7] = a[7] * inv + b1.w;
    #pragma unroll
    for (int i = 0; i < 8; ++i)
        r[i] = r[i] > 0.f ? r[i] : __expf(r[i]) - 1.f;   // elu
    float4 o0 = make_float4(x0.x + r[0], x0.y + r[1], x0.z + r[2], x0.w + r[3]);
    float4 o1 = make_float4(x1.x + r[4], x1.y + r[5], x1.z + r[6], x1.w + r[7]);
    *(float4*)(out + (size_t)node * DFEAT + c)     = o0;
    *(float4*)(out + (size_t)node * DFEAT + c + 4) = o1;
}

extern "C" void kernel_launch(void* const* d_in, const int* in_sizes, int n_in,
                              void* d_out, int out_size, void* d_ws, size_t ws_size,
                              hipStream_t stream)
{
    const float* x    = (const float*)d_in[0];
    const int*   edge = (const int*)d_in[1];
    const float* Wm   = (const float*)d_in[2];
    const float* avs  = (const float*)d_in[3];
    const float* avd  = (const float*)d_in[4];
    const float* bias = (const float*)d_in[5];

    const int D = DFEAT;
    const int N = in_sizes[0] / D;
    const int E = in_sizes[1] / 2;
    const int T = E + N;
    const int* srcv = edge;
    const int* dstv = edge + E;

    char* ws = (char*)d_ws;
    size_t off = 0;
    auto alloc = [&](size_t bytes) -> char* {
        char* p = ws + off;
        off += (bytes + 255) & ~(size_t)255;
        return p;
    };
    // zero region: cur[N] | es[N] | ed[N]
    int*   cur  = (int*)alloc((size_t)N * 3 * 4);
    float* es   = (float*)(cur + N);
    float* ed   = es + N;
    int*   slot = (int*)alloc((size_t)N * SLOTS * 4);
    unsigned short* Xb = (unsigned short*)alloc((size_t)N * D * 2);
    unsigned short* Wb = (unsigned short*)alloc((size_t)D * D * 2);
    unsigned short* H  = (unsigned short*)alloc((size_t)N * D * 2);

    hipMemsetAsync(cur, 0, (size_t)N * 3 * 4, stream);

    int nx4   = (N * D) / 4;
    int ntot4 = nx4 + (D * D) / 4;
    int grid0 = (ntot4 > T ? ntot4 : T);
    cvt_scatter_kernel<<<dim3((grid0 + 255) / 256), 256, 0, stream>>>(
        x, Wm, Xb, Wb, srcv, dstv, cur, slot, nx4, ntot4, E, T);

    int rowPanels  = (N + 127) / 128;          // 128-row tiles
    int rowPanels8 = ((rowPanels + 7) / 8) * 8;
    gemm_h_kernel<<<dim3(rowPanels8 * 8), 256, 0, stream>>>(
        Xb, Wb, avs, avd, H, es, ed, N);
    aggregate_kernel<<<dim3((N * 64 + 255) / 256), 256, 0, stream>>>(
        H, x, bias, cur, slot, es, ed, (float*)d_out, N);
}